// Round 1
// baseline (584.283 us; speedup 1.0000x reference)
//
#include <hip/hip_runtime.h>
#include <math.h>

#define B_ 16
#define T_ 2048
#define DIM_ 1024
#define MDIM_ 128
#define HID_ 512
#define NCAT 640
#define NW_ 128
#define WINSZ 16
#define MAXP_ 6
#define P_ 768
#define KDROP 614
#define TKEEP 1434
#define NTOK (B_*T_)

typedef unsigned short u16;
typedef __bf16 bf16x8 __attribute__((ext_vector_type(8)));
typedef float f32x4 __attribute__((ext_vector_type(4)));
typedef unsigned short us4 __attribute__((ext_vector_type(4)));

// ---------- fallback (fp32) workspace layout (float units) ----------
#define OFF_WCAT   0
#define OFF_BIAS   (OFF_WCAT + DIM_*NCAT)
#define OFF_MU     (OFF_BIAS + NCAT)
#define OFF_RS     (OFF_MU + NTOK)
#define OFF_MBUF   (OFF_RS + NTOK)
#define OFF_LOGIT  (OFF_MBUF + NTOK*MDIM_)
#define OFF_IIDX   (OFF_LOGIT + NTOK)
#define OFF_JIDX   (OFF_IIDX + B_*P_)
#define OFF_SV     (OFF_JIDX + B_*P_)
#define OFF_ALPHA  (OFF_SV + B_*P_)
#define OFF_REP    (OFF_ALPHA + B_*P_)
#define OFF_DROP   (OFF_REP + NTOK)
#define OFF_POS    (OFF_DROP + NTOK)

// ---------- fast-path workspace layout (float units) ----------
static constexpr size_t F_AH    = 0;                                    // NTOK*DIM_ u16
static constexpr size_t F_AL    = F_AH + (size_t)NTOK*DIM_/2;
static constexpr size_t F_BH    = F_AL + (size_t)NTOK*DIM_/2;           // NCAT*DIM_ u16 (transposed)
static constexpr size_t F_BL    = F_BH + (size_t)NCAT*DIM_/2;
static constexpr size_t F_BIAS  = F_BL + (size_t)NCAT*DIM_/2;
static constexpr size_t F_MBUF  = F_BIAS + NCAT;
static constexpr size_t F_LOGIT = F_MBUF + (size_t)NTOK*MDIM_;
static constexpr size_t F_IIDX  = F_LOGIT + NTOK;
static constexpr size_t F_JIDX  = F_IIDX + (size_t)B_*P_;
static constexpr size_t F_SV    = F_JIDX + (size_t)B_*P_;
static constexpr size_t F_ALPHA = F_SV + (size_t)B_*P_;
static constexpr size_t F_REP   = F_ALPHA + (size_t)B_*P_;
static constexpr size_t F_DROP  = F_REP + NTOK;
static constexpr size_t F_POS   = F_DROP + NTOK;
static constexpr size_t F_TOTAL = F_POS + NTOK;

// ---------------- helpers ----------------
__device__ __forceinline__ u16 f2bf(float f) {
  unsigned u = __builtin_bit_cast(unsigned, f);
  unsigned r = u + 0x7FFFu + ((u >> 16) & 1u);
  return (u16)(r >> 16);
}
__device__ __forceinline__ float bf2f(u16 h) {
  unsigned u = ((unsigned)h) << 16;
  return __builtin_bit_cast(float, u);
}
__device__ __forceinline__ void gll16(const void* g, void* l) {
  __builtin_amdgcn_global_load_lds((const __attribute__((address_space(1))) void*)g,
                                   (__attribute__((address_space(3))) void*)l, 16, 0, 0);
}

// ================= fast path kernels =================

// prep_a: LN stats + x-hat + bf16 hi/lo split, one wave per token.
// Also zeroes logit[token] (replaces the hipMemsetAsync dispatch).
__global__ __launch_bounds__(256) void prep_a(const float* __restrict__ x,
    u16* __restrict__ Ah, u16* __restrict__ Al, float* __restrict__ logit) {
  int token = blockIdx.x * 4 + (threadIdx.x >> 6);
  int lane = threadIdx.x & 63;
  if (lane == 0) logit[token] = 0.f;
  const float4* xr = (const float4*)(x + (size_t)token * DIM_);
  float4 v[4];
  float sum = 0.f;
#pragma unroll
  for (int it = 0; it < 4; ++it) {
    v[it] = xr[lane + it * 64];
    sum += v[it].x + v[it].y + v[it].z + v[it].w;
  }
  for (int o = 32; o > 0; o >>= 1) sum += __shfl_xor(sum, o);
  float m = sum * (1.f / 1024.f);
  float ss = 0.f;
#pragma unroll
  for (int it = 0; it < 4; ++it) {
    float a = v[it].x - m, b = v[it].y - m, c = v[it].z - m, d = v[it].w - m;
    ss += a * a + b * b + c * c + d * d;
  }
  for (int o = 32; o > 0; o >>= 1) ss += __shfl_xor(ss, o);
  float rsv = 1.0f / sqrtf(ss * (1.f / 1024.f) + 1e-5f);
#pragma unroll
  for (int it = 0; it < 4; ++it) {
    float e[4] = {(v[it].x - m) * rsv, (v[it].y - m) * rsv,
                  (v[it].z - m) * rsv, (v[it].w - m) * rsv};
    us4 hv, lv;
#pragma unroll
    for (int j = 0; j < 4; ++j) {
      u16 h = f2bf(e[j]);
      hv[j] = h;
      lv[j] = f2bf(e[j] - bf2f(h));
    }
    size_t off = (size_t)token * DIM_ + (size_t)(lane + it * 64) * 4;
    *(us4*)&Ah[off] = hv;
    *(us4*)&Al[off] = lv;
  }
}

// prep_w: fused prep_b (Bt split hi/lo) + bias projection
__global__ __launch_bounds__(256) void prep_w(const float* __restrict__ wm,
    const float* __restrict__ wi, const float* __restrict__ gm,
    const float* __restrict__ gi, const float* __restrict__ bm,
    const float* __restrict__ bi, const float* __restrict__ b1,
    u16* __restrict__ Bh, u16* __restrict__ Bl, float* __restrict__ biascat) {
  int bid = blockIdx.x;
  const int NBLK_B = (NCAT * DIM_) / 256;
  if (bid < NBLK_B) {
    int e = bid * 256 + threadIdx.x;  // n*1024 + k
    int n = e >> 10, k = e & 1023;
    float wv = (n < MDIM_) ? gm[k] * wm[k * MDIM_ + n]
                           : gi[k] * wi[k * HID_ + (n - MDIM_)];
    u16 h = f2bf(wv);
    Bh[e] = h;
    Bl[e] = f2bf(wv - bf2f(h));
  } else {
    int c = bid - NBLK_B;
    float s = 0.f;
    for (int k = threadIdx.x; k < DIM_; k += 256)
      s += (c < MDIM_) ? bm[k] * wm[k * MDIM_ + c]
                       : bi[k] * wi[k * HID_ + (c - MDIM_)];
    __shared__ float red[256];
    red[threadIdx.x] = s; __syncthreads();
    for (int o = 128; o > 0; o >>= 1) {
      if (threadIdx.x < o) red[threadIdx.x] += red[threadIdx.x + o];
      __syncthreads();
    }
    if (threadIdx.x == 0)
      biascat[c] = red[0] + ((c >= MDIM_) ? b1[c - MDIM_] : 0.f);
  }
}

// gemm_mfma: C[32768x640] = (Ah+Al)@(Bh+Bl)^T via 3-product bf16 MFMA
// 128x128 tile, BK=32. A (hi+lo) double-buffered in LDS via gll16 (32 KB).
// B (hi+lo, 2.6 MB total => L2-resident) is loaded per k-step DIRECTLY into
// MFMA operand registers: no LDS, no ds_read, no staging waves for B.
// B loads are issued BEFORE the A gll16 prefetch (pinned by sched_barrier)
// so the MFMA's wait is a counted vmcnt(4): the HBM A-prefetch stays in
// flight across the compute. LDS 64->32 KB + launch_bounds(256,3) lifts
// residency from 2 to 3 blocks/CU for cross-block overlap at the barrier.
__global__ __launch_bounds__(256, 3) void gemm_mfma(
    const u16* __restrict__ Ah, const u16* __restrict__ Al,
    const u16* __restrict__ Bh, const u16* __restrict__ Bl,
    const float* __restrict__ biascat, const float* __restrict__ w2,
    float* __restrict__ mbuf, float* __restrict__ logit) {
  __shared__ __align__(16) u16 sAH[2][8 * 512];
  __shared__ __align__(16) u16 sAL[2][8 * 512];
  const int tid = threadIdx.x;
  const int w = tid >> 6, lane = tid & 63;
  // XCD-aware swizzle: 5 col-tiles of a row-stripe share one XCD (ids == mod 8)
  int bid = blockIdx.x;
  int q = bid / 40, rem = bid % 40;
  int ct = rem >> 3, x8 = rem & 7;
  int stripe = x8 + 8 * q;
  const int row0 = stripe * 128, col0 = ct * 128;
  const int wy = w >> 1, wx = w & 1;
  const int m16 = lane & 15, quad = lane >> 4;

  // A staging duty: w0 -> AH tiles 0-3, w1 -> AH tiles 4-7,
  //                 w2 -> AL tiles 0-3, w3 -> AL tiles 4-7
  const u16* gA = (w < 2) ? Ah : Al;
  const int th = (w & 1) * 4;
  const u16* gsrcA = gA + (size_t)(row0 + th * 16 + m16) * DIM_ + quad * 8;
  u16* ldsA0 = ((w < 2) ? sAH[0] : sAL[0]) + th * 512 + lane * 8;
  u16* ldsA1 = ((w < 2) ? sAH[1] : sAL[1]) + th * 512 + lane * 8;

  // B fragment pointers: lane (m16,quad) -> B[col0+wx*64+j*16+m16][quad*8..+8]
  const size_t nb0 = (size_t)(col0 + wx * 64 + m16) * DIM_ + (size_t)(quad * 8);
  const u16* pbh0 = Bh + nb0;
  const u16* pbh1 = pbh0 + 16 * DIM_;
  const u16* pbh2 = pbh0 + 32 * DIM_;
  const u16* pbh3 = pbh0 + 48 * DIM_;
  const u16* pbl0 = Bl + nb0;
  const u16* pbl1 = pbl0 + 16 * DIM_;
  const u16* pbl2 = pbl0 + 32 * DIM_;
  const u16* pbl3 = pbl0 + 48 * DIM_;

  // preload k-step 0 (A only) into buffer 0
#pragma unroll
  for (int t = 0; t < 4; ++t)
    gll16(gsrcA + (size_t)t * 16 * DIM_, ldsA0 + t * 512);

  f32x4 acc[4][4] = {};
  for (int k0 = 0; k0 < 32; ++k0) {
    __syncthreads();  // drains vmcnt -> A buf[k0&1] staged
    // --- B register loads for THIS k-step (L2-hit, ~200cyc) issued FIRST ---
    bf16x8 bh0 = *(const bf16x8*)pbh0;
    bf16x8 bh1 = *(const bf16x8*)pbh1;
    bf16x8 bh2 = *(const bf16x8*)pbh2;
    bf16x8 bh3 = *(const bf16x8*)pbh3;
    bf16x8 bl0 = *(const bf16x8*)pbl0;
    bf16x8 bl1 = *(const bf16x8*)pbl1;
    bf16x8 bl2 = *(const bf16x8*)pbl2;
    bf16x8 bl3 = *(const bf16x8*)pbl3;
    // pin: keep the gll16 prefetch AFTER the B loads so the B-use wait is a
    // counted vmcnt(4) (A prefetch allowed to stay outstanding)
    __builtin_amdgcn_sched_barrier(0);
    if (k0 + 1 < 32) {
      u16* nb = (k0 & 1) ? ldsA0 : ldsA1;
#pragma unroll
      for (int t = 0; t < 4; ++t)
        gll16(gsrcA + (size_t)t * 16 * DIM_ + (k0 + 1) * 32, nb + t * 512);
    }
    const int cb = k0 & 1;
    bf16x8 ah[4], al[4];
#pragma unroll
    for (int i = 0; i < 4; ++i) {
      ah[i] = *(const bf16x8*)&sAH[cb][(wy * 4 + i) * 512 + lane * 8];
      al[i] = *(const bf16x8*)&sAL[cb][(wy * 4 + i) * 512 + lane * 8];
    }
#pragma unroll
    for (int i = 0; i < 4; ++i) {
      acc[i][0] = __builtin_amdgcn_mfma_f32_16x16x32_bf16(ah[i], bh0, acc[i][0], 0, 0, 0);
      acc[i][1] = __builtin_amdgcn_mfma_f32_16x16x32_bf16(ah[i], bh1, acc[i][1], 0, 0, 0);
      acc[i][2] = __builtin_amdgcn_mfma_f32_16x16x32_bf16(ah[i], bh2, acc[i][2], 0, 0, 0);
      acc[i][3] = __builtin_amdgcn_mfma_f32_16x16x32_bf16(ah[i], bh3, acc[i][3], 0, 0, 0);
      acc[i][0] = __builtin_amdgcn_mfma_f32_16x16x32_bf16(ah[i], bl0, acc[i][0], 0, 0, 0);
      acc[i][1] = __builtin_amdgcn_mfma_f32_16x16x32_bf16(ah[i], bl1, acc[i][1], 0, 0, 0);
      acc[i][2] = __builtin_amdgcn_mfma_f32_16x16x32_bf16(ah[i], bl2, acc[i][2], 0, 0, 0);
      acc[i][3] = __builtin_amdgcn_mfma_f32_16x16x32_bf16(ah[i], bl3, acc[i][3], 0, 0, 0);
      acc[i][0] = __builtin_amdgcn_mfma_f32_16x16x32_bf16(al[i], bh0, acc[i][0], 0, 0, 0);
      acc[i][1] = __builtin_amdgcn_mfma_f32_16x16x32_bf16(al[i], bh1, acc[i][1], 0, 0, 0);
      acc[i][2] = __builtin_amdgcn_mfma_f32_16x16x32_bf16(al[i], bh2, acc[i][2], 0, 0, 0);
      acc[i][3] = __builtin_amdgcn_mfma_f32_16x16x32_bf16(al[i], bh3, acc[i][3], 0, 0, 0);
    }
    pbh0 += 32; pbh1 += 32; pbh2 += 32; pbh3 += 32;
    pbl0 += 32; pbl1 += 32; pbl2 += 32; pbl3 += 32;
  }
  // epilogue: C/D layout col=lane&15 (n), row=quad*4+r (m)
  if (ct == 0) {
#pragma unroll
    for (int i = 0; i < 4; ++i)
#pragma unroll
      for (int j = 0; j < 4; ++j) {
        int col = wx * 64 + j * 16 + m16;
        float bs = biascat[col];
#pragma unroll
        for (int r = 0; r < 4; ++r) {
          int row = row0 + wy * 64 + i * 16 + quad * 4 + r;
          mbuf[(size_t)row * MDIM_ + col] = acc[i][j][r] + bs;
        }
      }
  } else {
#pragma unroll
    for (int i = 0; i < 4; ++i) {
      float part[4] = {0.f, 0.f, 0.f, 0.f};
#pragma unroll
      for (int j = 0; j < 4; ++j) {
        int col = col0 + wx * 64 + j * 16 + m16;
        float bs = biascat[col];
        float wv = w2[col - MDIM_];
#pragma unroll
        for (int r = 0; r < 4; ++r) {
          float v = acc[i][j][r] + bs;
          v = v > 0.f ? v : 0.f;
          part[r] += v * wv;
        }
      }
#pragma unroll
      for (int r = 0; r < 4; ++r) {
        part[r] += __shfl_xor(part[r], 1);
        part[r] += __shfl_xor(part[r], 2);
        part[r] += __shfl_xor(part[r], 4);
        part[r] += __shfl_xor(part[r], 8);
      }
      if (m16 == 0)
#pragma unroll
        for (int r = 0; r < 4; ++r)
          atomicAdd(&logit[row0 + wy * 64 + i * 16 + quad * 4 + r], part[r]);
    }
  }
}

// ================= shared kernels (both paths) =================

// simgreedy: loads raw m rows, normalizes IN LDS (rows are window-private),
// then sim + greedy matching. One wave per window.
__global__ __launch_bounds__(256) void simgreedy(const float* __restrict__ mbuf,
    int* __restrict__ ii, int* __restrict__ jj, float* __restrict__ sv) {
  __shared__ __align__(16) float sm[4][16][132];
  int wv = threadIdx.x >> 6, lane = threadIdx.x & 63;
  int win = blockIdx.x * 4 + wv;
  int b = win >> 7, w = win & 127;
  size_t base = ((size_t)b * T_ + w * WINSZ) * MDIM_;
#pragma unroll
  for (int it = 0; it < 8; ++it) {
    int e4 = it * 64 + lane;
    int row = e4 >> 5, c4 = e4 & 31;
    float4 v = *(const float4*)(mbuf + base + (size_t)row * MDIM_ + c4 * 4);
    *(float4*)&sm[wv][row][c4 * 4] = v;
  }
  __syncthreads();
  // normalize each of the 16 rows: 4 lanes per row
  {
    int row = lane >> 2, seg = lane & 3;
    float* r = sm[wv][row] + seg * 32;
    float ss = 0.f;
#pragma unroll
    for (int k = 0; k < 32; ++k) ss += r[k] * r[k];
    ss += __shfl_xor(ss, 1);
    ss += __shfl_xor(ss, 2);
    float inv = 1.0f / sqrtf(ss);
#pragma unroll
    for (int k = 0; k < 32; ++k) r[k] *= inv;
  }
  __syncthreads();
  int a = lane >> 3, c = lane & 7;
  const float* ev = sm[wv][2 * a];
  const float* od = sm[wv][2 * c + 1];
  float s = 0.f;
#pragma unroll
  for (int k = 0; k < MDIM_; ++k) s += ev[k] * od[k];
  if (s < -10.0f) s = -__builtin_inff();
  float v = s;
  bool alive = true;
  int outb = (b * NW_ + w) * MAXP_;
  for (int p = 0; p < MAXP_; ++p) {
    float bv = alive ? v : -__builtin_inff();
    int bi = lane;
    for (int o = 32; o > 0; o >>= 1) {
      float ov = __shfl_xor(bv, o);
      int oi = __shfl_xor(bi, o);
      if (ov > bv || (ov == bv && oi < bi)) { bv = ov; bi = oi; }
    }
    int wa = bi >> 3, wc = bi & 7;
    if (lane == 0) {
      ii[outb + p] = w * WINSZ + 2 * wa;
      jj[outb + p] = w * WINSZ + 2 * wc + 1;
      sv[outb + p] = bv;
    }
    if (a == wa || c == wc) alive = false;
  }
}

// select_fused: imp (sigmoid of logit) + scores + exact stable top-k +
// alpha + rep/drop + per-batch prefix (pos). One block per batch.
__global__ __launch_bounds__(256) void select_fused(const float* __restrict__ sv,
    const int* __restrict__ ii, const int* __restrict__ jj,
    const float* __restrict__ logit, const float* __restrict__ b2,
    float* __restrict__ alpha, int* __restrict__ rep,
    int* __restrict__ drop, int* __restrict__ pos) {
  int b = blockIdx.x, tid = threadIdx.x;
  __shared__ float sc[P_];
  __shared__ int sdrop[T_];
  __shared__ int wtot[4];
  float bb = b2[0];
  for (int t = tid; t < T_; t += 256) {
    sdrop[t] = 0;
    rep[b * T_ + t] = -1;
  }
  for (int p = tid; p < P_; p += 256) {
    int i = ii[b * P_ + p], j = jj[b * P_ + p];
    float fi = 1.f / (1.f + expf(-(logit[b * T_ + i] + bb)));
    float fj = 1.f / (1.f + expf(-(logit[b * T_ + j] + bb)));
    sc[p] = sv[b * P_ + p] - 0.25f * (fi + fj);
    alpha[b * P_ + p] = 1.f / (1.f + expf(-5.f * (fi - fj)));
  }
  __syncthreads();
  for (int p = tid; p < P_; p += 256) {
    float s = sc[p];
    int cnt = 0;
    for (int q = 0; q < P_; ++q) {
      float t = sc[q];
      cnt += (t > s) || (t == s && q < p);
    }
    if (cnt < KDROP) {
      rep[b * T_ + ii[b * P_ + p]] = p;
      sdrop[jj[b * P_ + p]] = 1;
    }
  }
  __syncthreads();
  // prefix over keep mask: 8 tokens per thread
  int base = tid * 8;
  int loc[8];
  int s = 0;
#pragma unroll
  for (int k = 0; k < 8; ++k) { loc[k] = s; s += (sdrop[base + k] ? 0 : 1); }
  int lane = tid & 63, wvi = tid >> 6;
  int incl = s;
  for (int o = 1; o < 64; o <<= 1) {
    int n = __shfl_up(incl, o);
    if (lane >= o) incl += n;
  }
  if (lane == 63) wtot[wvi] = incl;
  __syncthreads();
  int carry = 0;
  for (int ww = 0; ww < wvi; ++ww) carry += wtot[ww];
  int excl = carry + incl - s;
#pragma unroll
  for (int k = 0; k < 8; ++k) {
    int t = base + k;
    drop[b * T_ + t] = sdrop[t];
    pos[b * T_ + t] = excl + loc[k];
  }
}

// pack: 8 tokens per block (grid 4096 instead of 32768 tiny dispatches)
__global__ __launch_bounds__(256) void pack_kernel(const float* __restrict__ x,
    const int* __restrict__ drop, const int* __restrict__ pos,
    const int* __restrict__ rep, const float* __restrict__ alpha,
    const int* __restrict__ jj, float* __restrict__ out) {
  int b = blockIdx.y;
  int t0 = blockIdx.x * 8;
  int tid = threadIdx.x;
  const int bT = b * T_;
#pragma unroll 1
  for (int tt = 0; tt < 8; ++tt) {
    int t = t0 + tt;
    if (drop[bT + t]) continue;
    const float4* xi = (const float4*)(x + ((size_t)bT + t) * DIM_);
    float4 v = xi[tid];
    int p = rep[bT + t];
    if (p >= 0) {
      float a = alpha[b * P_ + p];
      int j = jj[b * P_ + p];
      const float4* xj = (const float4*)(x + ((size_t)bT + j) * DIM_);
      float4 vj = xj[tid];
      v.x = a * v.x + (1.f - a) * vj.x;
      v.y = a * v.y + (1.f - a) * vj.y;
      v.z = a * v.z + (1.f - a) * vj.z;
      v.w = a * v.w + (1.f - a) * vj.w;
    }
    int np = pos[bT + t];
    ((float4*)(out + ((size_t)b * TKEEP + np) * DIM_))[tid] = v;
  }
}

// ================= fallback fp32 GEMM path =================

__global__ __launch_bounds__(256) void build_wcat(const float* __restrict__ wm,
    const float* __restrict__ wi, const float* __restrict__ gm,
    const float* __restrict__ gi, float* __restrict__ Wcat) {
  int e = blockIdx.x * 256 + threadIdx.x;
  if (e >= DIM_ * NCAT) return;
  int k = e / NCAT, c = e - k * NCAT;
  float v = (c < MDIM_) ? gm[k] * wm[k * MDIM_ + c]
                        : gi[k] * wi[k * HID_ + (c - MDIM_)];
  Wcat[e] = v;
}

__global__ __launch_bounds__(256) void build_bias(const float* __restrict__ wm,
    const float* __restrict__ wi, const float* __restrict__ bm,
    const float* __restrict__ bi, const float* __restrict__ b1,
    float* __restrict__ biascat) {
  int c = blockIdx.x;
  float s = 0.f;
  for (int k = threadIdx.x; k < DIM_; k += 256)
    s += (c < MDIM_) ? bm[k] * wm[k * MDIM_ + c]
                     : bi[k] * wi[k * HID_ + (c - MDIM_)];
  __shared__ float red[256];
  red[threadIdx.x] = s; __syncthreads();
  for (int o = 128; o > 0; o >>= 1) {
    if (threadIdx.x < o) red[threadIdx.x] += red[threadIdx.x + o];
    __syncthreads();
  }
  if (threadIdx.x == 0)
    biascat[c] = red[0] + ((c >= MDIM_) ? b1[c - MDIM_] : 0.f);
}

__global__ __launch_bounds__(256) void ln_stats(const float* __restrict__ x,
    float* __restrict__ mu, float* __restrict__ rs) {
  int token = blockIdx.x * 4 + (threadIdx.x >> 6);
  int lane = threadIdx.x & 63;
  const float4* xr = (const float4*)(x + (size_t)token * DIM_);
  float4 v[4];
  float sum = 0.f;
#pragma unroll
  for (int it = 0; it < 4; ++it) {
    v[it] = xr[lane + it * 64];
    sum += v[it].x + v[it].y + v[it].z + v[it].w;
  }
  for (int o = 32; o > 0; o >>= 1) sum += __shfl_xor(sum, o);
  float m = sum * (1.f / 1024.f);
  float ss = 0.f;
#pragma unroll
  for (int it = 0; it < 4; ++it) {
    float a = v[it].x - m, b = v[it].y - m, c = v[it].z - m, d = v[it].w - m;
    ss += a * a + b * b + c * c + d * d;
  }
  for (int o = 32; o > 0; o >>= 1) ss += __shfl_xor(ss, o);
  if (lane == 0) {
    mu[token] = m;
    rs[token] = 1.0f / sqrtf(ss * (1.f / 1024.f) + 1e-5f);
  }
}

__global__ __launch_bounds__(256) void gemm640(const float* __restrict__ x,
    const float* __restrict__ mu, const float* __restrict__ rs,
    const float* __restrict__ Wcat, const float* __restrict__ biascat,
    const float* __restrict__ w2, float* __restrict__ mbuf,
    float* __restrict__ logit) {
  __shared__ __align__(16) float As[16][68];
  __shared__ __align__(16) float Bs[16][68];
  const int tid = threadIdx.x;
  const int row0 = blockIdx.x * 64, col0 = blockIdx.y * 64;
  const int tx = tid & 15, ty = tid >> 4;
  const int arow = tid >> 2, akk = (tid & 3) << 2;
  const int brow = tid >> 4, bnn = (tid & 15) << 2;
  const int t_g = row0 + arow;
  const float tmu = mu[t_g], trs = rs[t_g];
  const float* xrow = x + (size_t)t_g * DIM_ + akk;
  const float* wptr = Wcat + (size_t)brow * NCAT + col0 + bnn;
  float acc[4][4] = {};
  for (int k0 = 0; k0 < DIM_; k0 += 16) {
    float4 av = *(const float4*)(xrow + k0);
    float4 bv = *(const float4*)(wptr + (size_t)k0 * NCAT);
    As[akk + 0][arow] = (av.x - tmu) * trs;
    As[akk + 1][arow] = (av.y - tmu) * trs;
    As[akk + 2][arow] = (av.z - tmu) * trs;
    As[akk + 3][arow] = (av.w - tmu) * trs;
    *(float4*)&Bs[brow][bnn] = bv;
    __syncthreads();
#pragma unroll
    for (int k = 0; k < 16; ++k) {
      float4 a = *(const float4*)&As[k][ty << 2];
      float4 b = *(const float4*)&Bs[k][tx << 2];
      acc[0][0] += a.x * b.x; acc[0][1] += a.x * b.y; acc[0][2] += a.x * b.z; acc[0][3] += a.x * b.w;
      acc[1][0] += a.y * b.x; acc[1][1] += a.y * b.y; acc[1][2] += a.y * b.z; acc[1][3] += a.y * b.w;
      acc[2][0] += a.z * b.x; acc[2][1] += a.z * b.y; acc[2][2] += a.z * b.z; acc[2][3] += a.z * b.w;
      acc[3][0] += a.w * b.x; acc[3][1] += a.w * b.y; acc[3][2] += a.w * b.z; acc[3][3] += a.w * b.w;
    }
    __syncthreads();
  }
  float bias[4];
#pragma unroll
  for (int j = 0; j < 4; ++j) bias[j] = biascat[col0 + (tx << 2) + j];
  if (col0 < MDIM_) {
#pragma unroll
    for (int i = 0; i < 4; ++i) {
      int t = row0 + (ty << 2) + i;
      float4 o;
      o.x = acc[i][0] + bias[0]; o.y = acc[i][1] + bias[1];
      o.z = acc[i][2] + bias[2]; o.w = acc[i][3] + bias[3];
      *(float4*)(mbuf + (size_t)t * MDIM_ + col0 + (tx << 2)) = o;
    }
  } else {
    float w2v[4];
#pragma unroll
    for (int j = 0; j < 4; ++j) w2v[j] = w2[col0 - MDIM_ + (tx << 2) + j];
#pragma unroll
    for (int i = 0; i < 4; ++i) {
      float p = 0.f;
#pragma unroll
      for (int j = 0; j < 4; ++j) {
        float v = acc[i][j] + bias[j];
        v = v > 0.f ? v : 0.f;
        p += v * w2v[j];
      }
      p += __shfl_xor(p, 1); p += __shfl_xor(p, 2);
      p += __shfl_xor(p, 4); p += __shfl_xor(p, 8);
      if (tx == 0) atomicAdd(&logit[row0 + (ty << 2) + i], p);
    }
  }
}

extern "C" void kernel_launch(void* const* d_in, const int* in_sizes, int n_in,
                              void* d_out, int out_size, void* d_ws, size_t ws_size,
                              hipStream_t stream) {
  const float* x    = (const float*)d_in[0];
  const float* gm   = (const float*)d_in[1];
  const float* bm   = (const float*)d_in[2];
  const float* wm   = (const float*)d_in[3];
  const float* gi   = (const float*)d_in[4];
  const float* bi   = (const float*)d_in[5];
  const float* wi   = (const float*)d_in[6];
  const float* b1   = (const float*)d_in[7];
  const float* w2   = (const float*)d_in[8];
  const float* b2   = (const float*)d_in[9];
  float* ws = (float*)d_ws;
  float* out = (float*)d_out;

  if (ws_size >= F_TOTAL * sizeof(float)) {
    // -------- fast path: bf16x2-split MFMA GEMM (B from L2 into regs) --------
    u16* Ah = (u16*)(ws + F_AH);
    u16* Al = (u16*)(ws + F_AL);
    u16* Bh = (u16*)(ws + F_BH);
    u16* Bl = (u16*)(ws + F_BL);
    float* bias  = ws + F_BIAS;
    float* mbuf  = ws + F_MBUF;
    float* logit = ws + F_LOGIT;
    int* iidx    = (int*)(ws + F_IIDX);
    int* jidx    = (int*)(ws + F_JIDX);
    float* sv    = ws + F_SV;
    float* alpha = ws + F_ALPHA;
    int* rep     = (int*)(ws + F_REP);
    int* drop    = (int*)(ws + F_DROP);
    int* pos     = (int*)(ws + F_POS);

    prep_w<<<(NCAT * DIM_) / 256 + NCAT, 256, 0, stream>>>(wm, wi, gm, gi, bm, bi, b1, Bh, Bl, bias);
    prep_a<<<NTOK / 4, 256, 0, stream>>>(x, Ah, Al, logit);
    gemm_mfma<<<(NTOK / 128) * (NCAT / 128), 256, 0, stream>>>(Ah, Al, Bh, Bl, bias, w2, mbuf, logit);
    simgreedy<<<(B_ * NW_) / 4, 256, 0, stream>>>(mbuf, iidx, jidx, sv);
    select_fused<<<B_, 256, 0, stream>>>(sv, iidx, jidx, logit, b2, alpha, rep, drop, pos);
    dim3 pgrid(T_ / 8, B_);
    pack_kernel<<<pgrid, 256, 0, stream>>>(x, drop, pos, rep, alpha, jidx, out);
  } else {
    // -------- fallback: fp32 vector-ALU path --------
    float* Wcat = ws + OFF_WCAT;
    float* bias = ws + OFF_BIAS;
    float* mu   = ws + OFF_MU;
    float* rs   = ws + OFF_RS;
    float* mbuf = ws + OFF_MBUF;
    float* logit = ws + OFF_LOGIT;
    int* iidx   = (int*)(ws + OFF_IIDX);
    int* jidx   = (int*)(ws + OFF_JIDX);
    float* sv   = ws + OFF_SV;
    float* alpha = ws + OFF_ALPHA;
    int* rep    = (int*)(ws + OFF_REP);
    int* drop   = (int*)(ws + OFF_DROP);
    int* pos    = (int*)(ws + OFF_POS);

    hipMemsetAsync(logit, 0, NTOK * sizeof(float), stream);
    build_wcat<<<(DIM_ * NCAT + 255) / 256, 256, 0, stream>>>(wm, wi, gm, gi, Wcat);
    build_bias<<<NCAT, 256, 0, stream>>>(wm, wi, bm, bi, b1, bias);
    ln_stats<<<NTOK / 4, 256, 0, stream>>>(x, mu, rs);
    dim3 ggrid(NTOK / 64, NCAT / 64);
    gemm640<<<ggrid, 256, 0, stream>>>(x, mu, rs, Wcat, bias, w2, mbuf, logit);
    simgreedy<<<(B_ * NW_) / 4, 256, 0, stream>>>(mbuf, iidx, jidx, sv);
    select_fused<<<B_, 256, 0, stream>>>(sv, iidx, jidx, logit, b2, alpha, rep, drop, pos);
    dim3 pgrid(T_ / 8, B_);
    pack_kernel<<<pgrid, 256, 0, stream>>>(x, drop, pos, rep, alpha, jidx, out);
  }
}

// Round 2
// 481.407 us; speedup vs baseline: 1.2137x; 1.2137x over previous
//
#include <hip/hip_runtime.h>
#include <math.h>

#define B_ 16
#define T_ 2048
#define DIM_ 1024
#define MDIM_ 128
#define HID_ 512
#define NCAT 640
#define NW_ 128
#define WINSZ 16
#define MAXP_ 6
#define P_ 768
#define KDROP 614
#define TKEEP 1434
#define NTOK (B_*T_)

typedef unsigned short u16;
typedef __bf16 bf16x8 __attribute__((ext_vector_type(8)));
typedef float f32x4 __attribute__((ext_vector_type(4)));
typedef unsigned short us4 __attribute__((ext_vector_type(4)));

// ---------- fallback (fp32) workspace layout (float units) ----------
#define OFF_WCAT   0
#define OFF_BIAS   (OFF_WCAT + DIM_*NCAT)
#define OFF_MU     (OFF_BIAS + NCAT)
#define OFF_RS     (OFF_MU + NTOK)
#define OFF_MBUF   (OFF_RS + NTOK)
#define OFF_LOGIT  (OFF_MBUF + NTOK*MDIM_)
#define OFF_IIDX   (OFF_LOGIT + NTOK)
#define OFF_JIDX   (OFF_IIDX + B_*P_)
#define OFF_SV     (OFF_JIDX + B_*P_)
#define OFF_ALPHA  (OFF_SV + B_*P_)
#define OFF_REP    (OFF_ALPHA + B_*P_)
#define OFF_DROP   (OFF_REP + NTOK)
#define OFF_POS    (OFF_DROP + NTOK)

// ---------- fast-path workspace layout (float units) ----------
static constexpr size_t F_AH    = 0;                                    // NTOK*DIM_ u16
static constexpr size_t F_AL    = F_AH + (size_t)NTOK*DIM_/2;
static constexpr size_t F_BH    = F_AL + (size_t)NTOK*DIM_/2;           // NCAT*DIM_ u16 (transposed)
static constexpr size_t F_BL    = F_BH + (size_t)NCAT*DIM_/2;
static constexpr size_t F_BIAS  = F_BL + (size_t)NCAT*DIM_/2;
static constexpr size_t F_MBUF  = F_BIAS + NCAT;
static constexpr size_t F_LOGIT = F_MBUF + (size_t)NTOK*MDIM_;
static constexpr size_t F_IIDX  = F_LOGIT + NTOK;
static constexpr size_t F_JIDX  = F_IIDX + (size_t)B_*P_;
static constexpr size_t F_SV    = F_JIDX + (size_t)B_*P_;
static constexpr size_t F_ALPHA = F_SV + (size_t)B_*P_;
static constexpr size_t F_REP   = F_ALPHA + (size_t)B_*P_;
static constexpr size_t F_DROP  = F_REP + NTOK;
static constexpr size_t F_POS   = F_DROP + NTOK;
static constexpr size_t F_TOTAL = F_POS + NTOK;

// ---------------- helpers ----------------
__device__ __forceinline__ u16 f2bf(float f) {
  unsigned u = __builtin_bit_cast(unsigned, f);
  unsigned r = u + 0x7FFFu + ((u >> 16) & 1u);
  return (u16)(r >> 16);
}
__device__ __forceinline__ float bf2f(u16 h) {
  unsigned u = ((unsigned)h) << 16;
  return __builtin_bit_cast(float, u);
}
__device__ __forceinline__ void gll16(const void* g, void* l) {
  __builtin_amdgcn_global_load_lds((const __attribute__((address_space(1))) void*)g,
                                   (__attribute__((address_space(3))) void*)l, 16, 0, 0);
}

// ================= fast path kernels =================

// prep_all: fused prep_a (LN + bf16 hi/lo split of x, one wave per token,
// also zeroes logit) + prep_w (weight split hi/lo + bias projection).
// One dispatch instead of two: removes a full-drain boundary and overlaps
// the small weight prep under the big token prep.
#define NBLK_A (NTOK / 4)                 // 8192 blocks, 4 tokens each
#define NBLK_B ((NCAT * DIM_) / 256)      // 2560 blocks
__global__ __launch_bounds__(256) void prep_all(const float* __restrict__ x,
    const float* __restrict__ wm, const float* __restrict__ wi,
    const float* __restrict__ gm, const float* __restrict__ gi,
    const float* __restrict__ bm, const float* __restrict__ bi,
    const float* __restrict__ b1,
    u16* __restrict__ Ah, u16* __restrict__ Al,
    u16* __restrict__ Bh, u16* __restrict__ Bl,
    float* __restrict__ biascat, float* __restrict__ logit) {
  int bid = blockIdx.x;
  if (bid < NBLK_A) {
    // ---- prep_a branch ----
    int token = bid * 4 + (threadIdx.x >> 6);
    int lane = threadIdx.x & 63;
    if (lane == 0) logit[token] = 0.f;
    const float4* xr = (const float4*)(x + (size_t)token * DIM_);
    float4 v[4];
    float sum = 0.f;
#pragma unroll
    for (int it = 0; it < 4; ++it) {
      v[it] = xr[lane + it * 64];
      sum += v[it].x + v[it].y + v[it].z + v[it].w;
    }
    for (int o = 32; o > 0; o >>= 1) sum += __shfl_xor(sum, o);
    float m = sum * (1.f / 1024.f);
    float ss = 0.f;
#pragma unroll
    for (int it = 0; it < 4; ++it) {
      float a = v[it].x - m, b = v[it].y - m, c = v[it].z - m, d = v[it].w - m;
      ss += a * a + b * b + c * c + d * d;
    }
    for (int o = 32; o > 0; o >>= 1) ss += __shfl_xor(ss, o);
    float rsv = 1.0f / sqrtf(ss * (1.f / 1024.f) + 1e-5f);
#pragma unroll
    for (int it = 0; it < 4; ++it) {
      float e[4] = {(v[it].x - m) * rsv, (v[it].y - m) * rsv,
                    (v[it].z - m) * rsv, (v[it].w - m) * rsv};
      us4 hv, lv;
#pragma unroll
      for (int j = 0; j < 4; ++j) {
        u16 h = f2bf(e[j]);
        hv[j] = h;
        lv[j] = f2bf(e[j] - bf2f(h));
      }
      size_t off = (size_t)token * DIM_ + (size_t)(lane + it * 64) * 4;
      *(us4*)&Ah[off] = hv;
      *(us4*)&Al[off] = lv;
    }
  } else if (bid < NBLK_A + NBLK_B) {
    // ---- weight split branch ----
    int e = (bid - NBLK_A) * 256 + threadIdx.x;  // n*1024 + k
    int n = e >> 10, k = e & 1023;
    float wv = (n < MDIM_) ? gm[k] * wm[k * MDIM_ + n]
                           : gi[k] * wi[k * HID_ + (n - MDIM_)];
    u16 h = f2bf(wv);
    Bh[e] = h;
    Bl[e] = f2bf(wv - bf2f(h));
  } else {
    // ---- bias projection branch ----
    int c = bid - NBLK_A - NBLK_B;
    float s = 0.f;
    for (int k = threadIdx.x; k < DIM_; k += 256)
      s += (c < MDIM_) ? bm[k] * wm[k * MDIM_ + c]
                       : bi[k] * wi[k * HID_ + (c - MDIM_)];
    __shared__ float red[256];
    red[threadIdx.x] = s; __syncthreads();
    for (int o = 128; o > 0; o >>= 1) {
      if (threadIdx.x < o) red[threadIdx.x] += red[threadIdx.x + o];
      __syncthreads();
    }
    if (threadIdx.x == 0)
      biascat[c] = red[0] + ((c >= MDIM_) ? b1[c - MDIM_] : 0.f);
  }
}

// gemm_mfma: C[32768x640] = (Ah+Al)@(Bh+Bl)^T via 3-product bf16 MFMA
// 128x128 tile, BK=32, DOUBLE-BUFFERED LDS: prefetch k+1 issued before compute
// of k, so ~500 cyc of MFMA+ds_read hides the load latency at the barrier.
// (r1 lesson: loading B straight from L2 into regs exposes 200-900cyc of
// VMEM latency on the MFMA path every k-step -> 250us. Keep B in LDS.)
__global__ __launch_bounds__(256, 2) void gemm_mfma(
    const u16* __restrict__ Ah, const u16* __restrict__ Al,
    const u16* __restrict__ Bh, const u16* __restrict__ Bl,
    const float* __restrict__ biascat, const float* __restrict__ w2,
    float* __restrict__ mbuf, float* __restrict__ logit) {
  __shared__ __align__(16) u16 sAH[2][8 * 512];
  __shared__ __align__(16) u16 sAL[2][8 * 512];
  __shared__ __align__(16) u16 sBH[2][8 * 512];
  __shared__ __align__(16) u16 sBL[2][8 * 512];
  const int tid = threadIdx.x;
  const int w = tid >> 6, lane = tid & 63;
  // XCD-aware swizzle: 5 col-tiles of a row-stripe share one XCD (ids == mod 8)
  int bid = blockIdx.x;
  int q = bid / 40, rem = bid % 40;
  int ct = rem >> 3, x8 = rem & 7;
  int stripe = x8 + 8 * q;
  const int row0 = stripe * 128, col0 = ct * 128;
  const int wy = w >> 1, wx = w & 1;
  const int m16 = lane & 15, quad = lane >> 4;

  // staging duty: wave0->AH, wave1->AL, wave2->BH, wave3->BL (8 tiles each)
  const u16* gA = (w == 0) ? Ah : (w == 1) ? Al : (w == 2) ? Bh : Bl;
  u16* lds0 = ((w == 0) ? sAH[0] : (w == 1) ? sAL[0] : (w == 2) ? sBH[0] : sBL[0]) + lane * 8;
  u16* lds1 = ((w == 0) ? sAH[1] : (w == 1) ? sAL[1] : (w == 2) ? sBH[1] : sBL[1]) + lane * 8;
  const int rbase = (w < 2) ? row0 : col0;
  const u16* gsrc0 = gA + (size_t)(rbase + m16) * DIM_ + quad * 8;

  // preload k-step 0 into buffer 0
#pragma unroll
  for (int t = 0; t < 8; ++t)
    gll16(gsrc0 + (size_t)t * 16 * DIM_, lds0 + t * 512);

  f32x4 acc[4][4] = {};
  for (int k0 = 0; k0 < 32; ++k0) {
    __syncthreads();  // drains vmcnt -> buf[k0&1] staged; prev reads of other buf done
    if (k0 + 1 < 32) {
      u16* nb = (k0 & 1) ? lds0 : lds1;   // next buffer index = (k0+1)&1
#pragma unroll
      for (int t = 0; t < 8; ++t)
        gll16(gsrc0 + (size_t)t * 16 * DIM_ + (k0 + 1) * 32, nb + t * 512);
    }
    const int cb = k0 & 1;
    bf16x8 ah[4], al[4], bh[4], bl[4];
#pragma unroll
    for (int i = 0; i < 4; ++i) {
      ah[i] = *(const bf16x8*)&sAH[cb][(wy * 4 + i) * 512 + lane * 8];
      al[i] = *(const bf16x8*)&sAL[cb][(wy * 4 + i) * 512 + lane * 8];
      bh[i] = *(const bf16x8*)&sBH[cb][(wx * 4 + i) * 512 + lane * 8];
      bl[i] = *(const bf16x8*)&sBL[cb][(wx * 4 + i) * 512 + lane * 8];
    }
#pragma unroll
    for (int i = 0; i < 4; ++i)
#pragma unroll
      for (int j = 0; j < 4; ++j) {
        acc[i][j] = __builtin_amdgcn_mfma_f32_16x16x32_bf16(ah[i], bh[j], acc[i][j], 0, 0, 0);
        acc[i][j] = __builtin_amdgcn_mfma_f32_16x16x32_bf16(ah[i], bl[j], acc[i][j], 0, 0, 0);
        acc[i][j] = __builtin_amdgcn_mfma_f32_16x16x32_bf16(al[i], bh[j], acc[i][j], 0, 0, 0);
      }
  }
  // epilogue: C/D layout col=lane&15 (n), row=quad*4+r (m)
  if (ct == 0) {
#pragma unroll
    for (int i = 0; i < 4; ++i)
#pragma unroll
      for (int j = 0; j < 4; ++j) {
        int col = wx * 64 + j * 16 + m16;
        float bs = biascat[col];
#pragma unroll
        for (int r = 0; r < 4; ++r) {
          int row = row0 + wy * 64 + i * 16 + quad * 4 + r;
          mbuf[(size_t)row * MDIM_ + col] = acc[i][j][r] + bs;
        }
      }
  } else {
#pragma unroll
    for (int i = 0; i < 4; ++i) {
      float part[4] = {0.f, 0.f, 0.f, 0.f};
#pragma unroll
      for (int j = 0; j < 4; ++j) {
        int col = col0 + wx * 64 + j * 16 + m16;
        float bs = biascat[col];
        float wv = w2[col - MDIM_];
#pragma unroll
        for (int r = 0; r < 4; ++r) {
          float v = acc[i][j][r] + bs;
          v = v > 0.f ? v : 0.f;
          part[r] += v * wv;
        }
      }
#pragma unroll
      for (int r = 0; r < 4; ++r) {
        part[r] += __shfl_xor(part[r], 1);
        part[r] += __shfl_xor(part[r], 2);
        part[r] += __shfl_xor(part[r], 4);
        part[r] += __shfl_xor(part[r], 8);
      }
      if (m16 == 0)
#pragma unroll
        for (int r = 0; r < 4; ++r)
          atomicAdd(&logit[row0 + wy * 64 + i * 16 + quad * 4 + r], part[r]);
    }
  }
}

// ================= shared kernels (both paths) =================

// simgreedy: loads raw m rows, normalizes IN LDS (rows are window-private),
// then sim + greedy matching. One wave per window.
__global__ __launch_bounds__(256) void simgreedy(const float* __restrict__ mbuf,
    int* __restrict__ ii, int* __restrict__ jj, float* __restrict__ sv) {
  __shared__ __align__(16) float sm[4][16][132];
  int wv = threadIdx.x >> 6, lane = threadIdx.x & 63;
  int win = blockIdx.x * 4 + wv;
  int b = win >> 7, w = win & 127;
  size_t base = ((size_t)b * T_ + w * WINSZ) * MDIM_;
#pragma unroll
  for (int it = 0; it < 8; ++it) {
    int e4 = it * 64 + lane;
    int row = e4 >> 5, c4 = e4 & 31;
    float4 v = *(const float4*)(mbuf + base + (size_t)row * MDIM_ + c4 * 4);
    *(float4*)&sm[wv][row][c4 * 4] = v;
  }
  __syncthreads();
  // normalize each of the 16 rows: 4 lanes per row
  {
    int row = lane >> 2, seg = lane & 3;
    float* r = sm[wv][row] + seg * 32;
    float ss = 0.f;
#pragma unroll
    for (int k = 0; k < 32; ++k) ss += r[k] * r[k];
    ss += __shfl_xor(ss, 1);
    ss += __shfl_xor(ss, 2);
    float inv = 1.0f / sqrtf(ss);
#pragma unroll
    for (int k = 0; k < 32; ++k) r[k] *= inv;
  }
  __syncthreads();
  int a = lane >> 3, c = lane & 7;
  const float* ev = sm[wv][2 * a];
  const float* od = sm[wv][2 * c + 1];
  float s = 0.f;
#pragma unroll
  for (int k = 0; k < MDIM_; ++k) s += ev[k] * od[k];
  if (s < -10.0f) s = -__builtin_inff();
  float v = s;
  bool alive = true;
  int outb = (b * NW_ + w) * MAXP_;
  for (int p = 0; p < MAXP_; ++p) {
    float bv = alive ? v : -__builtin_inff();
    int bi = lane;
    for (int o = 32; o > 0; o >>= 1) {
      float ov = __shfl_xor(bv, o);
      int oi = __shfl_xor(bi, o);
      if (ov > bv || (ov == bv && oi < bi)) { bv = ov; bi = oi; }
    }
    int wa = bi >> 3, wc = bi & 7;
    if (lane == 0) {
      ii[outb + p] = w * WINSZ + 2 * wa;
      jj[outb + p] = w * WINSZ + 2 * wc + 1;
      sv[outb + p] = bv;
    }
    if (a == wa || c == wc) alive = false;
  }
}

// select_fused: imp (sigmoid of logit) + scores + exact stable top-k +
// alpha + rep/drop + per-batch prefix (pos). One block per batch.
// 1024 threads: one p per thread (was 3) -> 3x less serial O(P) work on a
// kernel that only occupies 16 CUs.
__global__ __launch_bounds__(1024) void select_fused(const float* __restrict__ sv,
    const int* __restrict__ ii, const int* __restrict__ jj,
    const float* __restrict__ logit, const float* __restrict__ b2,
    float* __restrict__ alpha, int* __restrict__ rep,
    int* __restrict__ drop, int* __restrict__ pos) {
  int b = blockIdx.x, tid = threadIdx.x;
  __shared__ float sc[P_];
  __shared__ int sdrop[T_];
  __shared__ int wtot[16];
  float bb = b2[0];
  for (int t = tid; t < T_; t += 1024) {
    sdrop[t] = 0;
    rep[b * T_ + t] = -1;
  }
  if (tid < P_) {
    int i = ii[b * P_ + tid], j = jj[b * P_ + tid];
    float fi = 1.f / (1.f + expf(-(logit[b * T_ + i] + bb)));
    float fj = 1.f / (1.f + expf(-(logit[b * T_ + j] + bb)));
    sc[tid] = sv[b * P_ + tid] - 0.25f * (fi + fj);
    alpha[b * P_ + tid] = 1.f / (1.f + expf(-5.f * (fi - fj)));
  }
  __syncthreads();
  if (tid < P_) {
    float s = sc[tid];
    int cnt = 0;
    for (int qq = 0; qq < P_; ++qq) {
      float t = sc[qq];
      cnt += (t > s) || (t == s && qq < tid);
    }
    if (cnt < KDROP) {
      rep[b * T_ + ii[b * P_ + tid]] = tid;
      sdrop[jj[b * P_ + tid]] = 1;
    }
  }
  __syncthreads();
  // prefix over keep mask: 2 tokens per thread
  int base = tid * 2;
  int loc0 = 0;
  int loc1 = (sdrop[base] ? 0 : 1);
  int s = loc1 + (sdrop[base + 1] ? 0 : 1);
  int lane = tid & 63, wvi = tid >> 6;
  int incl = s;
  for (int o = 1; o < 64; o <<= 1) {
    int n = __shfl_up(incl, o);
    if (lane >= o) incl += n;
  }
  if (lane == 63) wtot[wvi] = incl;
  __syncthreads();
  int carry = 0;
  for (int ww = 0; ww < wvi; ++ww) carry += wtot[ww];
  int excl = carry + incl - s;
  drop[b * T_ + base] = sdrop[base];
  drop[b * T_ + base + 1] = sdrop[base + 1];
  pos[b * T_ + base] = excl + loc0;
  pos[b * T_ + base + 1] = excl + loc1;
}

// pack: one token per block (full TLP; serial-loop variant was latency-bound)
__global__ __launch_bounds__(256) void pack_kernel(const float* __restrict__ x,
    const int* __restrict__ drop, const int* __restrict__ pos,
    const int* __restrict__ rep, const float* __restrict__ alpha,
    const int* __restrict__ jj, float* __restrict__ out) {
  int t = blockIdx.x, b = blockIdx.y;
  if (drop[b * T_ + t]) return;
  int tid = threadIdx.x;
  const float4* xi = (const float4*)(x + ((size_t)b * T_ + t) * DIM_);
  float4 v = xi[tid];
  int p = rep[b * T_ + t];
  if (p >= 0) {
    float a = alpha[b * P_ + p];
    int j = jj[b * P_ + p];
    const float4* xj = (const float4*)(x + ((size_t)b * T_ + j) * DIM_);
    float4 vj = xj[tid];
    v.x = a * v.x + (1.f - a) * vj.x;
    v.y = a * v.y + (1.f - a) * vj.y;
    v.z = a * v.z + (1.f - a) * vj.z;
    v.w = a * v.w + (1.f - a) * vj.w;
  }
  int np = pos[b * T_ + t];
  ((float4*)(out + ((size_t)b * TKEEP + np) * DIM_))[tid] = v;
}

// ================= fallback fp32 GEMM path =================

__global__ __launch_bounds__(256) void build_wcat(const float* __restrict__ wm,
    const float* __restrict__ wi, const float* __restrict__ gm,
    const float* __restrict__ gi, float* __restrict__ Wcat) {
  int e = blockIdx.x * 256 + threadIdx.x;
  if (e >= DIM_ * NCAT) return;
  int k = e / NCAT, c = e - k * NCAT;
  float v = (c < MDIM_) ? gm[k] * wm[k * MDIM_ + c]
                        : gi[k] * wi[k * HID_ + (c - MDIM_)];
  Wcat[e] = v;
}

__global__ __launch_bounds__(256) void build_bias(const float* __restrict__ wm,
    const float* __restrict__ wi, const float* __restrict__ bm,
    const float* __restrict__ bi, const float* __restrict__ b1,
    float* __restrict__ biascat) {
  int c = blockIdx.x;
  float s = 0.f;
  for (int k = threadIdx.x; k < DIM_; k += 256)
    s += (c < MDIM_) ? bm[k] * wm[k * MDIM_ + c]
                     : bi[k] * wi[k * HID_ + (c - MDIM_)];
  __shared__ float red[256];
  red[threadIdx.x] = s; __syncthreads();
  for (int o = 128; o > 0; o >>= 1) {
    if (threadIdx.x < o) red[threadIdx.x] += red[threadIdx.x + o];
    __syncthreads();
  }
  if (threadIdx.x == 0)
    biascat[c] = red[0] + ((c >= MDIM_) ? b1[c - MDIM_] : 0.f);
}

__global__ __launch_bounds__(256) void ln_stats(const float* __restrict__ x,
    float* __restrict__ mu, float* __restrict__ rs) {
  int token = blockIdx.x * 4 + (threadIdx.x >> 6);
  int lane = threadIdx.x & 63;
  const float4* xr = (const float4*)(x + (size_t)token * DIM_);
  float4 v[4];
  float sum = 0.f;
#pragma unroll
  for (int it = 0; it < 4; ++it) {
    v[it] = xr[lane + it * 64];
    sum += v[it].x + v[it].y + v[it].z + v[it].w;
  }
  for (int o = 32; o > 0; o >>= 1) sum += __shfl_xor(sum, o);
  float m = sum * (1.f / 1024.f);
  float ss = 0.f;
#pragma unroll
  for (int it = 0; it < 4; ++it) {
    float a = v[it].x - m, b = v[it].y - m, c = v[it].z - m, d = v[it].w - m;
    ss += a * a + b * b + c * c + d * d;
  }
  for (int o = 32; o > 0; o >>= 1) ss += __shfl_xor(ss, o);
  if (lane == 0) {
    mu[token] = m;
    rs[token] = 1.0f / sqrtf(ss * (1.f / 1024.f) + 1e-5f);
  }
}

__global__ __launch_bounds__(256) void gemm640(const float* __restrict__ x,
    const float* __restrict__ mu, const float* __restrict__ rs,
    const float* __restrict__ Wcat, const float* __restrict__ biascat,
    const float* __restrict__ w2, float* __restrict__ mbuf,
    float* __restrict__ logit) {
  __shared__ __align__(16) float As[16][68];
  __shared__ __align__(16) float Bs[16][68];
  const int tid = threadIdx.x;
  const int row0 = blockIdx.x * 64, col0 = blockIdx.y * 64;
  const int tx = tid & 15, ty = tid >> 4;
  const int arow = tid >> 2, akk = (tid & 3) << 2;
  const int brow = tid >> 4, bnn = (tid & 15) << 2;
  const int t_g = row0 + arow;
  const float tmu = mu[t_g], trs = rs[t_g];
  const float* xrow = x + (size_t)t_g * DIM_ + akk;
  const float* wptr = Wcat + (size_t)brow * NCAT + col0 + bnn;
  float acc[4][4] = {};
  for (int k0 = 0; k0 < DIM_; k0 += 16) {
    float4 av = *(const float4*)(xrow + k0);
    float4 bv = *(const float4*)(wptr + (size_t)k0 * NCAT);
    As[akk + 0][arow] = (av.x - tmu) * trs;
    As[akk + 1][arow] = (av.y - tmu) * trs;
    As[akk + 2][arow] = (av.z - tmu) * trs;
    As[akk + 3][arow] = (av.w - tmu) * trs;
    *(float4*)&Bs[brow][bnn] = bv;
    __syncthreads();
#pragma unroll
    for (int k = 0; k < 16; ++k) {
      float4 a = *(const float4*)&As[k][ty << 2];
      float4 b = *(const float4*)&Bs[k][tx << 2];
      acc[0][0] += a.x * b.x; acc[0][1] += a.x * b.y; acc[0][2] += a.x * b.z; acc[0][3] += a.x * b.w;
      acc[1][0] += a.y * b.x; acc[1][1] += a.y * b.y; acc[1][2] += a.y * b.z; acc[1][3] += a.y * b.w;
      acc[2][0] += a.z * b.x; acc[2][1] += a.z * b.y; acc[2][2] += a.z * b.z; acc[2][3] += a.z * b.w;
      acc[3][0] += a.w * b.x; acc[3][1] += a.w * b.y; acc[3][2] += a.w * b.z; acc[3][3] += a.w * b.w;
    }
    __syncthreads();
  }
  float bias[4];
#pragma unroll
  for (int j = 0; j < 4; ++j) bias[j] = biascat[col0 + (tx << 2) + j];
  if (col0 < MDIM_) {
#pragma unroll
    for (int i = 0; i < 4; ++i) {
      int t = row0 + (ty << 2) + i;
      float4 o;
      o.x = acc[i][0] + bias[0]; o.y = acc[i][1] + bias[1];
      o.z = acc[i][2] + bias[2]; o.w = acc[i][3] + bias[3];
      *(float4*)(mbuf + (size_t)t * MDIM_ + col0 + (tx << 2)) = o;
    }
  } else {
    float w2v[4];
#pragma unroll
    for (int j = 0; j < 4; ++j) w2v[j] = w2[col0 - MDIM_ + (tx << 2) + j];
#pragma unroll
    for (int i = 0; i < 4; ++i) {
      float p = 0.f;
#pragma unroll
      for (int j = 0; j < 4; ++j) {
        float v = acc[i][j] + bias[j];
        v = v > 0.f ? v : 0.f;
        p += v * w2v[j];
      }
      p += __shfl_xor(p, 1); p += __shfl_xor(p, 2);
      p += __shfl_xor(p, 4); p += __shfl_xor(p, 8);
      if (tx == 0) atomicAdd(&logit[row0 + (ty << 2) + i], p);
    }
  }
}

extern "C" void kernel_launch(void* const* d_in, const int* in_sizes, int n_in,
                              void* d_out, int out_size, void* d_ws, size_t ws_size,
                              hipStream_t stream) {
  const float* x    = (const float*)d_in[0];
  const float* gm   = (const float*)d_in[1];
  const float* bm   = (const float*)d_in[2];
  const float* wm   = (const float*)d_in[3];
  const float* gi   = (const float*)d_in[4];
  const float* bi   = (const float*)d_in[5];
  const float* wi   = (const float*)d_in[6];
  const float* b1   = (const float*)d_in[7];
  const float* w2   = (const float*)d_in[8];
  const float* b2   = (const float*)d_in[9];
  float* ws = (float*)d_ws;
  float* out = (float*)d_out;

  if (ws_size >= F_TOTAL * sizeof(float)) {
    // -------- fast path: bf16x2-split MFMA GEMM (double-buffered) --------
    u16* Ah = (u16*)(ws + F_AH);
    u16* Al = (u16*)(ws + F_AL);
    u16* Bh = (u16*)(ws + F_BH);
    u16* Bl = (u16*)(ws + F_BL);
    float* bias  = ws + F_BIAS;
    float* mbuf  = ws + F_MBUF;
    float* logit = ws + F_LOGIT;
    int* iidx    = (int*)(ws + F_IIDX);
    int* jidx    = (int*)(ws + F_JIDX);
    float* sv    = ws + F_SV;
    float* alpha = ws + F_ALPHA;
    int* rep     = (int*)(ws + F_REP);
    int* drop    = (int*)(ws + F_DROP);
    int* pos     = (int*)(ws + F_POS);

    prep_all<<<NBLK_A + NBLK_B + NCAT, 256, 0, stream>>>(
        x, wm, wi, gm, gi, bm, bi, b1, Ah, Al, Bh, Bl, bias, logit);
    gemm_mfma<<<(NTOK / 128) * (NCAT / 128), 256, 0, stream>>>(Ah, Al, Bh, Bl, bias, w2, mbuf, logit);
    simgreedy<<<(B_ * NW_) / 4, 256, 0, stream>>>(mbuf, iidx, jidx, sv);
    select_fused<<<B_, 1024, 0, stream>>>(sv, iidx, jidx, logit, b2, alpha, rep, drop, pos);
    dim3 pgrid(T_, B_);
    pack_kernel<<<pgrid, 256, 0, stream>>>(x, drop, pos, rep, alpha, jidx, out);
  } else {
    // -------- fallback: fp32 vector-ALU path --------
    float* Wcat = ws + OFF_WCAT;
    float* bias = ws + OFF_BIAS;
    float* mu   = ws + OFF_MU;
    float* rs   = ws + OFF_RS;
    float* mbuf = ws + OFF_MBUF;
    float* logit = ws + OFF_LOGIT;
    int* iidx   = (int*)(ws + OFF_IIDX);
    int* jidx   = (int*)(ws + OFF_JIDX);
    float* sv   = ws + OFF_SV;
    float* alpha = ws + OFF_ALPHA;
    int* rep    = (int*)(ws + OFF_REP);
    int* drop   = (int*)(ws + OFF_DROP);
    int* pos    = (int*)(ws + OFF_POS);

    hipMemsetAsync(logit, 0, NTOK * sizeof(float), stream);
    build_wcat<<<(DIM_ * NCAT + 255) / 256, 256, 0, stream>>>(wm, wi, gm, gi, Wcat);
    build_bias<<<NCAT, 256, 0, stream>>>(wm, wi, bm, bi, b1, bias);
    ln_stats<<<NTOK / 4, 256, 0, stream>>>(x, mu, rs);
    dim3 ggrid(NTOK / 64, NCAT / 64);
    gemm640<<<ggrid, 256, 0, stream>>>(x, mu, rs, Wcat, bias, w2, mbuf, logit);
    simgreedy<<<(B_ * NW_) / 4, 256, 0, stream>>>(mbuf, iidx, jidx, sv);
    select_fused<<<B_, 1024, 0, stream>>>(sv, iidx, jidx, logit, b2, alpha, rep, drop, pos);
    dim3 pgrid(T_, B_);
    pack_kernel<<<pgrid, 256, 0, stream>>>(x, drop, pos, rep, alpha, jidx, out);
  }
}

// Round 3
// 475.205 us; speedup vs baseline: 1.2295x; 1.0131x over previous
//
#include <hip/hip_runtime.h>
#include <math.h>

#define B_ 16
#define T_ 2048
#define DIM_ 1024
#define MDIM_ 128
#define HID_ 512
#define NCAT 640
#define NW_ 128
#define WINSZ 16
#define MAXP_ 6
#define P_ 768
#define KDROP 614
#define TKEEP 1434
#define NTOK (B_*T_)

typedef unsigned short u16;
typedef __bf16 bf16x8 __attribute__((ext_vector_type(8)));
typedef float f32x4 __attribute__((ext_vector_type(4)));
typedef unsigned short us4 __attribute__((ext_vector_type(4)));

// ---------- fallback (fp32) workspace layout (float units) ----------
#define OFF_WCAT   0
#define OFF_BIAS   (OFF_WCAT + DIM_*NCAT)
#define OFF_MU     (OFF_BIAS + NCAT)
#define OFF_RS     (OFF_MU + NTOK)
#define OFF_MBUF   (OFF_RS + NTOK)
#define OFF_LOGIT  (OFF_MBUF + NTOK*MDIM_)
#define OFF_IIDX   (OFF_LOGIT + NTOK)
#define OFF_JIDX   (OFF_IIDX + B_*P_)
#define OFF_SV     (OFF_JIDX + B_*P_)
#define OFF_ALPHA  (OFF_SV + B_*P_)
#define OFF_REP    (OFF_ALPHA + B_*P_)
#define OFF_DROP   (OFF_REP + NTOK)
#define OFF_POS    (OFF_DROP + NTOK)

// ---------- fast-path workspace layout (float units) ----------
static constexpr size_t F_AH    = 0;                                    // NTOK*DIM_ u16
static constexpr size_t F_AL    = F_AH + (size_t)NTOK*DIM_/2;
static constexpr size_t F_BH    = F_AL + (size_t)NTOK*DIM_/2;           // NCAT*DIM_ u16 (transposed)
static constexpr size_t F_BL    = F_BH + (size_t)NCAT*DIM_/2;
static constexpr size_t F_BIAS  = F_BL + (size_t)NCAT*DIM_/2;
static constexpr size_t F_MBUF  = F_BIAS + NCAT;
static constexpr size_t F_LOGIT = F_MBUF + (size_t)NTOK*MDIM_;
static constexpr size_t F_IIDX  = F_LOGIT + NTOK;
static constexpr size_t F_JIDX  = F_IIDX + (size_t)B_*P_;
static constexpr size_t F_SV    = F_JIDX + (size_t)B_*P_;
static constexpr size_t F_ALPHA = F_SV + (size_t)B_*P_;
static constexpr size_t F_REP   = F_ALPHA + (size_t)B_*P_;
static constexpr size_t F_DROP  = F_REP + NTOK;
static constexpr size_t F_POS   = F_DROP + NTOK;
static constexpr size_t F_TOTAL = F_POS + NTOK;

// ---------------- helpers ----------------
__device__ __forceinline__ u16 f2bf(float f) {
  unsigned u = __builtin_bit_cast(unsigned, f);
  unsigned r = u + 0x7FFFu + ((u >> 16) & 1u);
  return (u16)(r >> 16);
}
__device__ __forceinline__ float bf2f(u16 h) {
  unsigned u = ((unsigned)h) << 16;
  return __builtin_bit_cast(float, u);
}
__device__ __forceinline__ void gll16(const void* g, void* l) {
  __builtin_amdgcn_global_load_lds((const __attribute__((address_space(1))) void*)g,
                                   (__attribute__((address_space(3))) void*)l, 16, 0, 0);
}

// ================= fast path kernels =================

// prep_all: fused prep_a (LN + bf16 hi/lo split of x, one wave per token,
// also zeroes logit) + prep_w (weight split hi/lo + bias projection).
#define NBLK_A (NTOK / 4)                 // 8192 blocks, 4 tokens each
#define NBLK_B ((NCAT * DIM_) / 256)      // 2560 blocks
__global__ __launch_bounds__(256) void prep_all(const float* __restrict__ x,
    const float* __restrict__ wm, const float* __restrict__ wi,
    const float* __restrict__ gm, const float* __restrict__ gi,
    const float* __restrict__ bm, const float* __restrict__ bi,
    const float* __restrict__ b1,
    u16* __restrict__ Ah, u16* __restrict__ Al,
    u16* __restrict__ Bh, u16* __restrict__ Bl,
    float* __restrict__ biascat, float* __restrict__ logit) {
  int bid = blockIdx.x;
  if (bid < NBLK_A) {
    // ---- prep_a branch ----
    int token = bid * 4 + (threadIdx.x >> 6);
    int lane = threadIdx.x & 63;
    if (lane == 0) logit[token] = 0.f;
    const float4* xr = (const float4*)(x + (size_t)token * DIM_);
    float4 v[4];
    float sum = 0.f;
#pragma unroll
    for (int it = 0; it < 4; ++it) {
      v[it] = xr[lane + it * 64];
      sum += v[it].x + v[it].y + v[it].z + v[it].w;
    }
    for (int o = 32; o > 0; o >>= 1) sum += __shfl_xor(sum, o);
    float m = sum * (1.f / 1024.f);
    float ss = 0.f;
#pragma unroll
    for (int it = 0; it < 4; ++it) {
      float a = v[it].x - m, b = v[it].y - m, c = v[it].z - m, d = v[it].w - m;
      ss += a * a + b * b + c * c + d * d;
    }
    for (int o = 32; o > 0; o >>= 1) ss += __shfl_xor(ss, o);
    float rsv = 1.0f / sqrtf(ss * (1.f / 1024.f) + 1e-5f);
#pragma unroll
    for (int it = 0; it < 4; ++it) {
      float e[4] = {(v[it].x - m) * rsv, (v[it].y - m) * rsv,
                    (v[it].z - m) * rsv, (v[it].w - m) * rsv};
      us4 hv, lv;
#pragma unroll
      for (int j = 0; j < 4; ++j) {
        u16 h = f2bf(e[j]);
        hv[j] = h;
        lv[j] = f2bf(e[j] - bf2f(h));
      }
      size_t off = (size_t)token * DIM_ + (size_t)(lane + it * 64) * 4;
      *(us4*)&Ah[off] = hv;
      *(us4*)&Al[off] = lv;
    }
  } else if (bid < NBLK_A + NBLK_B) {
    // ---- weight split branch ----
    int e = (bid - NBLK_A) * 256 + threadIdx.x;  // n*1024 + k
    int n = e >> 10, k = e & 1023;
    float wv = (n < MDIM_) ? gm[k] * wm[k * MDIM_ + n]
                           : gi[k] * wi[k * HID_ + (n - MDIM_)];
    u16 h = f2bf(wv);
    Bh[e] = h;
    Bl[e] = f2bf(wv - bf2f(h));
  } else {
    // ---- bias projection branch ----
    int c = bid - NBLK_A - NBLK_B;
    float s = 0.f;
    for (int k = threadIdx.x; k < DIM_; k += 256)
      s += (c < MDIM_) ? bm[k] * wm[k * MDIM_ + c]
                       : bi[k] * wi[k * HID_ + (c - MDIM_)];
    __shared__ float red[256];
    red[threadIdx.x] = s; __syncthreads();
    for (int o = 128; o > 0; o >>= 1) {
      if (threadIdx.x < o) red[threadIdx.x] += red[threadIdx.x + o];
      __syncthreads();
    }
    if (threadIdx.x == 0)
      biascat[c] = red[0] + ((c >= MDIM_) ? b1[c - MDIM_] : 0.f);
  }
}

// gemm_mfma: C[32768x640] = (Ah+Al)@(Bh+Bl)^T via 3-product bf16 MFMA.
// 128x128 tile, BK=32, depth-2 pipelined LDS with COUNTED vmcnt:
// r2 diagnosis: per k-step wall ~1850cyc vs ~860 busy -> ~1000cyc all-wave
// stall = HBM latency exposed by __syncthreads' vmcnt(0) drain.
// New schedule per iter k (raw s_barrier, no drain):
//   P1: ds_read frags(k); lgkmcnt(0); s_barrier   (buf[k&1] free to overwrite)
//   P2: issue stage(k+2) -> buf[k&1]
//   P3: 48 MFMA (register-only)
//   P4: s_waitcnt vmcnt(8) (stage(k+1) landed, stage(k+2) IN FLIGHT); s_barrier
// Loads get ~2 iterations of cover (>1800cyc) vs ~900cyc HBM latency.
__global__ __launch_bounds__(256, 2) void gemm_mfma(
    const u16* __restrict__ Ah, const u16* __restrict__ Al,
    const u16* __restrict__ Bh, const u16* __restrict__ Bl,
    const float* __restrict__ biascat, const float* __restrict__ w2,
    float* __restrict__ mbuf, float* __restrict__ logit) {
  __shared__ __align__(16) u16 sAH[2][8 * 512];
  __shared__ __align__(16) u16 sAL[2][8 * 512];
  __shared__ __align__(16) u16 sBH[2][8 * 512];
  __shared__ __align__(16) u16 sBL[2][8 * 512];
  const int tid = threadIdx.x;
  const int w = tid >> 6, lane = tid & 63;
  // XCD-aware swizzle: 5 col-tiles of a row-stripe share one XCD (ids == mod 8)
  int bid = blockIdx.x;
  int q = bid / 40, rem = bid % 40;
  int ct = rem >> 3, x8 = rem & 7;
  int stripe = x8 + 8 * q;
  const int row0 = stripe * 128, col0 = ct * 128;
  const int wy = w >> 1, wx = w & 1;
  const int m16 = lane & 15, quad = lane >> 4;

  // staging duty: wave0->AH, wave1->AL, wave2->BH, wave3->BL (8 tiles each)
  const u16* gA = (w == 0) ? Ah : (w == 1) ? Al : (w == 2) ? Bh : Bl;
  u16* lds0 = ((w == 0) ? sAH[0] : (w == 1) ? sAL[0] : (w == 2) ? sBH[0] : sBL[0]) + lane * 8;
  u16* lds1 = ((w == 0) ? sAH[1] : (w == 1) ? sAL[1] : (w == 2) ? sBH[1] : sBL[1]) + lane * 8;
  const int rbase = (w < 2) ? row0 : col0;
  const u16* gsrc0 = gA + (size_t)(rbase + m16) * DIM_ + quad * 8;

  // prologue: stage k=0 into buf0, k=1 into buf1; wait only for stage(0)
#pragma unroll
  for (int t = 0; t < 8; ++t)
    gll16(gsrc0 + (size_t)t * 16 * DIM_, lds0 + t * 512);
#pragma unroll
  for (int t = 0; t < 8; ++t)
    gll16(gsrc0 + (size_t)t * 16 * DIM_ + 32, lds1 + t * 512);
  __builtin_amdgcn_sched_barrier(0);
  asm volatile("s_waitcnt vmcnt(8)" ::: "memory");
  __builtin_amdgcn_s_barrier();
  __builtin_amdgcn_sched_barrier(0);

  f32x4 acc[4][4] = {};
  for (int k0 = 0; k0 < 32; ++k0) {
    const int cb = k0 & 1;
    // ---- P1: read all fragments of step k0 ----
    bf16x8 ah[4], al[4], bh[4], bl[4];
#pragma unroll
    for (int i = 0; i < 4; ++i) {
      ah[i] = *(const bf16x8*)&sAH[cb][(wy * 4 + i) * 512 + lane * 8];
      al[i] = *(const bf16x8*)&sAL[cb][(wy * 4 + i) * 512 + lane * 8];
      bh[i] = *(const bf16x8*)&sBH[cb][(wx * 4 + i) * 512 + lane * 8];
      bl[i] = *(const bf16x8*)&sBL[cb][(wx * 4 + i) * 512 + lane * 8];
    }
    __builtin_amdgcn_sched_barrier(0);
    asm volatile("s_waitcnt lgkmcnt(0)" ::: "memory");
    __builtin_amdgcn_sched_barrier(0);
    __builtin_amdgcn_s_barrier();   // all waves done READING buf[cb]
    __builtin_amdgcn_sched_barrier(0);
    // ---- P2: stage k0+2 into buf[cb] (just freed) ----
    if (k0 + 2 < 32) {
      u16* nb = cb ? lds1 : lds0;   // buf[(k0+2)&1] == buf[cb]
#pragma unroll
      for (int t = 0; t < 8; ++t)
        gll16(gsrc0 + (size_t)t * 16 * DIM_ + (k0 + 2) * 32, nb + t * 512);
    }
    __builtin_amdgcn_sched_barrier(0);
    // ---- P3: MFMA on registers ----
#pragma unroll
    for (int i = 0; i < 4; ++i)
#pragma unroll
      for (int j = 0; j < 4; ++j) {
        acc[i][j] = __builtin_amdgcn_mfma_f32_16x16x32_bf16(ah[i], bh[j], acc[i][j], 0, 0, 0);
        acc[i][j] = __builtin_amdgcn_mfma_f32_16x16x32_bf16(ah[i], bl[j], acc[i][j], 0, 0, 0);
        acc[i][j] = __builtin_amdgcn_mfma_f32_16x16x32_bf16(al[i], bh[j], acc[i][j], 0, 0, 0);
      }
    // ---- P4: stage(k0+1) landed (stage(k0+2) stays in flight); barrier ----
    __builtin_amdgcn_sched_barrier(0);
    if (k0 < 30) {
      asm volatile("s_waitcnt vmcnt(8)" ::: "memory");
    } else {
      asm volatile("s_waitcnt vmcnt(0)" ::: "memory");
    }
    __builtin_amdgcn_s_barrier();
    __builtin_amdgcn_sched_barrier(0);
  }
  // epilogue: C/D layout col=lane&15 (n), row=quad*4+r (m)
  if (ct == 0) {
#pragma unroll
    for (int i = 0; i < 4; ++i)
#pragma unroll
      for (int j = 0; j < 4; ++j) {
        int col = wx * 64 + j * 16 + m16;
        float bs = biascat[col];
#pragma unroll
        for (int r = 0; r < 4; ++r) {
          int row = row0 + wy * 64 + i * 16 + quad * 4 + r;
          mbuf[(size_t)row * MDIM_ + col] = acc[i][j][r] + bs;
        }
      }
  } else {
#pragma unroll
    for (int i = 0; i < 4; ++i) {
      float part[4] = {0.f, 0.f, 0.f, 0.f};
#pragma unroll
      for (int j = 0; j < 4; ++j) {
        int col = col0 + wx * 64 + j * 16 + m16;
        float bs = biascat[col];
        float wv = w2[col - MDIM_];
#pragma unroll
        for (int r = 0; r < 4; ++r) {
          float v = acc[i][j][r] + bs;
          v = v > 0.f ? v : 0.f;
          part[r] += v * wv;
        }
      }
#pragma unroll
      for (int r = 0; r < 4; ++r) {
        part[r] += __shfl_xor(part[r], 1);
        part[r] += __shfl_xor(part[r], 2);
        part[r] += __shfl_xor(part[r], 4);
        part[r] += __shfl_xor(part[r], 8);
      }
      if (m16 == 0)
#pragma unroll
        for (int r = 0; r < 4; ++r)
          atomicAdd(&logit[row0 + wy * 64 + i * 16 + quad * 4 + r], part[r]);
    }
  }
}

// ================= shared kernels (both paths) =================

// simgreedy: loads raw m rows, normalizes IN LDS (rows are window-private),
// then sim + greedy matching. One wave per window.
__global__ __launch_bounds__(256) void simgreedy(const float* __restrict__ mbuf,
    int* __restrict__ ii, int* __restrict__ jj, float* __restrict__ sv) {
  __shared__ __align__(16) float sm[4][16][132];
  int wv = threadIdx.x >> 6, lane = threadIdx.x & 63;
  int win = blockIdx.x * 4 + wv;
  int b = win >> 7, w = win & 127;
  size_t base = ((size_t)b * T_ + w * WINSZ) * MDIM_;
#pragma unroll
  for (int it = 0; it < 8; ++it) {
    int e4 = it * 64 + lane;
    int row = e4 >> 5, c4 = e4 & 31;
    float4 v = *(const float4*)(mbuf + base + (size_t)row * MDIM_ + c4 * 4);
    *(float4*)&sm[wv][row][c4 * 4] = v;
  }
  __syncthreads();
  // normalize each of the 16 rows: 4 lanes per row
  {
    int row = lane >> 2, seg = lane & 3;
    float* r = sm[wv][row] + seg * 32;
    float ss = 0.f;
#pragma unroll
    for (int k = 0; k < 32; ++k) ss += r[k] * r[k];
    ss += __shfl_xor(ss, 1);
    ss += __shfl_xor(ss, 2);
    float inv = 1.0f / sqrtf(ss);
#pragma unroll
    for (int k = 0; k < 32; ++k) r[k] *= inv;
  }
  __syncthreads();
  int a = lane >> 3, c = lane & 7;
  const float* ev = sm[wv][2 * a];
  const float* od = sm[wv][2 * c + 1];
  float s = 0.f;
#pragma unroll
  for (int k = 0; k < MDIM_; ++k) s += ev[k] * od[k];
  if (s < -10.0f) s = -__builtin_inff();
  float v = s;
  bool alive = true;
  int outb = (b * NW_ + w) * MAXP_;
  for (int p = 0; p < MAXP_; ++p) {
    float bv = alive ? v : -__builtin_inff();
    int bi = lane;
    for (int o = 32; o > 0; o >>= 1) {
      float ov = __shfl_xor(bv, o);
      int oi = __shfl_xor(bi, o);
      if (ov > bv || (ov == bv && oi < bi)) { bv = ov; bi = oi; }
    }
    int wa = bi >> 3, wc = bi & 7;
    if (lane == 0) {
      ii[outb + p] = w * WINSZ + 2 * wa;
      jj[outb + p] = w * WINSZ + 2 * wc + 1;
      sv[outb + p] = bv;
    }
    if (a == wa || c == wc) alive = false;
  }
}

// select_fused: imp (sigmoid of logit) + scores + exact stable top-k +
// alpha + rep/drop + per-batch prefix (pos). One block per batch, 1024 thr.
__global__ __launch_bounds__(1024) void select_fused(const float* __restrict__ sv,
    const int* __restrict__ ii, const int* __restrict__ jj,
    const float* __restrict__ logit, const float* __restrict__ b2,
    float* __restrict__ alpha, int* __restrict__ rep,
    int* __restrict__ drop, int* __restrict__ pos) {
  int b = blockIdx.x, tid = threadIdx.x;
  __shared__ float sc[P_];
  __shared__ int sdrop[T_];
  __shared__ int wtot[16];
  float bb = b2[0];
  for (int t = tid; t < T_; t += 1024) {
    sdrop[t] = 0;
    rep[b * T_ + t] = -1;
  }
  if (tid < P_) {
    int i = ii[b * P_ + tid], j = jj[b * P_ + tid];
    float fi = 1.f / (1.f + expf(-(logit[b * T_ + i] + bb)));
    float fj = 1.f / (1.f + expf(-(logit[b * T_ + j] + bb)));
    sc[tid] = sv[b * P_ + tid] - 0.25f * (fi + fj);
    alpha[b * P_ + tid] = 1.f / (1.f + expf(-5.f * (fi - fj)));
  }
  __syncthreads();
  if (tid < P_) {
    float s = sc[tid];
    int cnt = 0;
    for (int qq = 0; qq < P_; ++qq) {
      float t = sc[qq];
      cnt += (t > s) || (t == s && qq < tid);
    }
    if (cnt < KDROP) {
      rep[b * T_ + ii[b * P_ + tid]] = tid;
      sdrop[jj[b * P_ + tid]] = 1;
    }
  }
  __syncthreads();
  // prefix over keep mask: 2 tokens per thread
  int base = tid * 2;
  int loc0 = 0;
  int loc1 = (sdrop[base] ? 0 : 1);
  int s = loc1 + (sdrop[base + 1] ? 0 : 1);
  int lane = tid & 63, wvi = tid >> 6;
  int incl = s;
  for (int o = 1; o < 64; o <<= 1) {
    int n = __shfl_up(incl, o);
    if (lane >= o) incl += n;
  }
  if (lane == 63) wtot[wvi] = incl;
  __syncthreads();
  int carry = 0;
  for (int ww = 0; ww < wvi; ++ww) carry += wtot[ww];
  int excl = carry + incl - s;
  drop[b * T_ + base] = sdrop[base];
  drop[b * T_ + base + 1] = sdrop[base + 1];
  pos[b * T_ + base] = excl + loc0;
  pos[b * T_ + base + 1] = excl + loc1;
}

// pack: one token per block
__global__ __launch_bounds__(256) void pack_kernel(const float* __restrict__ x,
    const int* __restrict__ drop, const int* __restrict__ pos,
    const int* __restrict__ rep, const float* __restrict__ alpha,
    const int* __restrict__ jj, float* __restrict__ out) {
  int t = blockIdx.x, b = blockIdx.y;
  if (drop[b * T_ + t]) return;
  int tid = threadIdx.x;
  const float4* xi = (const float4*)(x + ((size_t)b * T_ + t) * DIM_);
  float4 v = xi[tid];
  int p = rep[b * T_ + t];
  if (p >= 0) {
    float a = alpha[b * P_ + p];
    int j = jj[b * P_ + p];
    const float4* xj = (const float4*)(x + ((size_t)b * T_ + j) * DIM_);
    float4 vj = xj[tid];
    v.x = a * v.x + (1.f - a) * vj.x;
    v.y = a * v.y + (1.f - a) * vj.y;
    v.z = a * v.z + (1.f - a) * vj.z;
    v.w = a * v.w + (1.f - a) * vj.w;
  }
  int np = pos[b * T_ + t];
  ((float4*)(out + ((size_t)b * TKEEP + np) * DIM_))[tid] = v;
}

// ================= fallback fp32 GEMM path =================

__global__ __launch_bounds__(256) void build_wcat(const float* __restrict__ wm,
    const float* __restrict__ wi, const float* __restrict__ gm,
    const float* __restrict__ gi, float* __restrict__ Wcat) {
  int e = blockIdx.x * 256 + threadIdx.x;
  if (e >= DIM_ * NCAT) return;
  int k = e / NCAT, c = e - k * NCAT;
  float v = (c < MDIM_) ? gm[k] * wm[k * MDIM_ + c]
                        : gi[k] * wi[k * HID_ + (c - MDIM_)];
  Wcat[e] = v;
}

__global__ __launch_bounds__(256) void build_bias(const float* __restrict__ wm,
    const float* __restrict__ wi, const float* __restrict__ bm,
    const float* __restrict__ bi, const float* __restrict__ b1,
    float* __restrict__ biascat) {
  int c = blockIdx.x;
  float s = 0.f;
  for (int k = threadIdx.x; k < DIM_; k += 256)
    s += (c < MDIM_) ? bm[k] * wm[k * MDIM_ + c]
                     : bi[k] * wi[k * HID_ + (c - MDIM_)];
  __shared__ float red[256];
  red[threadIdx.x] = s; __syncthreads();
  for (int o = 128; o > 0; o >>= 1) {
    if (threadIdx.x < o) red[threadIdx.x] += red[threadIdx.x + o];
    __syncthreads();
  }
  if (threadIdx.x == 0)
    biascat[c] = red[0] + ((c >= MDIM_) ? b1[c - MDIM_] : 0.f);
}

__global__ __launch_bounds__(256) void ln_stats(const float* __restrict__ x,
    float* __restrict__ mu, float* __restrict__ rs) {
  int token = blockIdx.x * 4 + (threadIdx.x >> 6);
  int lane = threadIdx.x & 63;
  const float4* xr = (const float4*)(x + (size_t)token * DIM_);
  float4 v[4];
  float sum = 0.f;
#pragma unroll
  for (int it = 0; it < 4; ++it) {
    v[it] = xr[lane + it * 64];
    sum += v[it].x + v[it].y + v[it].z + v[it].w;
  }
  for (int o = 32; o > 0; o >>= 1) sum += __shfl_xor(sum, o);
  float m = sum * (1.f / 1024.f);
  float ss = 0.f;
#pragma unroll
  for (int it = 0; it < 4; ++it) {
    float a = v[it].x - m, b = v[it].y - m, c = v[it].z - m, d = v[it].w - m;
    ss += a * a + b * b + c * c + d * d;
  }
  for (int o = 32; o > 0; o >>= 1) ss += __shfl_xor(ss, o);
  if (lane == 0) {
    mu[token] = m;
    rs[token] = 1.0f / sqrtf(ss * (1.f / 1024.f) + 1e-5f);
  }
}

__global__ __launch_bounds__(256) void gemm640(const float* __restrict__ x,
    const float* __restrict__ mu, const float* __restrict__ rs,
    const float* __restrict__ Wcat, const float* __restrict__ biascat,
    const float* __restrict__ w2, float* __restrict__ mbuf,
    float* __restrict__ logit) {
  __shared__ __align__(16) float As[16][68];
  __shared__ __align__(16) float Bs[16][68];
  const int tid = threadIdx.x;
  const int row0 = blockIdx.x * 64, col0 = blockIdx.y * 64;
  const int tx = tid & 15, ty = tid >> 4;
  const int arow = tid >> 2, akk = (tid & 3) << 2;
  const int brow = tid >> 4, bnn = (tid & 15) << 2;
  const int t_g = row0 + arow;
  const float tmu = mu[t_g], trs = rs[t_g];
  const float* xrow = x + (size_t)t_g * DIM_ + akk;
  const float* wptr = Wcat + (size_t)brow * NCAT + col0 + bnn;
  float acc[4][4] = {};
  for (int k0 = 0; k0 < DIM_; k0 += 16) {
    float4 av = *(const float4*)(xrow + k0);
    float4 bv = *(const float4*)(wptr + (size_t)k0 * NCAT);
    As[akk + 0][arow] = (av.x - tmu) * trs;
    As[akk + 1][arow] = (av.y - tmu) * trs;
    As[akk + 2][arow] = (av.z - tmu) * trs;
    As[akk + 3][arow] = (av.w - tmu) * trs;
    *(float4*)&Bs[brow][bnn] = bv;
    __syncthreads();
#pragma unroll
    for (int k = 0; k < 16; ++k) {
      float4 a = *(const float4*)&As[k][ty << 2];
      float4 b = *(const float4*)&Bs[k][tx << 2];
      acc[0][0] += a.x * b.x; acc[0][1] += a.x * b.y; acc[0][2] += a.x * b.z; acc[0][3] += a.x * b.w;
      acc[1][0] += a.y * b.x; acc[1][1] += a.y * b.y; acc[1][2] += a.y * b.z; acc[1][3] += a.y * b.w;
      acc[2][0] += a.z * b.x; acc[2][1] += a.z * b.y; acc[2][2] += a.z * b.z; acc[2][3] += a.z * b.w;
      acc[3][0] += a.w * b.x; acc[3][1] += a.w * b.y; acc[3][2] += a.w * b.z; acc[3][3] += a.w * b.w;
    }
    __syncthreads();
  }
  float bias[4];
#pragma unroll
  for (int j = 0; j < 4; ++j) bias[j] = biascat[col0 + (tx << 2) + j];
  if (col0 < MDIM_) {
#pragma unroll
    for (int i = 0; i < 4; ++i) {
      int t = row0 + (ty << 2) + i;
      float4 o;
      o.x = acc[i][0] + bias[0]; o.y = acc[i][1] + bias[1];
      o.z = acc[i][2] + bias[2]; o.w = acc[i][3] + bias[3];
      *(float4*)(mbuf + (size_t)t * MDIM_ + col0 + (tx << 2)) = o;
    }
  } else {
    float w2v[4];
#pragma unroll
    for (int j = 0; j < 4; ++j) w2v[j] = w2[col0 - MDIM_ + (tx << 2) + j];
#pragma unroll
    for (int i = 0; i < 4; ++i) {
      float p = 0.f;
#pragma unroll
      for (int j = 0; j < 4; ++j) {
        float v = acc[i][j] + bias[j];
        v = v > 0.f ? v : 0.f;
        p += v * w2v[j];
      }
      p += __shfl_xor(p, 1); p += __shfl_xor(p, 2);
      p += __shfl_xor(p, 4); p += __shfl_xor(p, 8);
      if (tx == 0) atomicAdd(&logit[row0 + (ty << 2) + i], p);
    }
  }
}

extern "C" void kernel_launch(void* const* d_in, const int* in_sizes, int n_in,
                              void* d_out, int out_size, void* d_ws, size_t ws_size,
                              hipStream_t stream) {
  const float* x    = (const float*)d_in[0];
  const float* gm   = (const float*)d_in[1];
  const float* bm   = (const float*)d_in[2];
  const float* wm   = (const float*)d_in[3];
  const float* gi   = (const float*)d_in[4];
  const float* bi   = (const float*)d_in[5];
  const float* wi   = (const float*)d_in[6];
  const float* b1   = (const float*)d_in[7];
  const float* w2   = (const float*)d_in[8];
  const float* b2   = (const float*)d_in[9];
  float* ws = (float*)d_ws;
  float* out = (float*)d_out;

  if (ws_size >= F_TOTAL * sizeof(float)) {
    // -------- fast path: bf16x2-split MFMA GEMM (counted-vmcnt pipeline) ----
    u16* Ah = (u16*)(ws + F_AH);
    u16* Al = (u16*)(ws + F_AL);
    u16* Bh = (u16*)(ws + F_BH);
    u16* Bl = (u16*)(ws + F_BL);
    float* bias  = ws + F_BIAS;
    float* mbuf  = ws + F_MBUF;
    float* logit = ws + F_LOGIT;
    int* iidx    = (int*)(ws + F_IIDX);
    int* jidx    = (int*)(ws + F_JIDX);
    float* sv    = ws + F_SV;
    float* alpha = ws + F_ALPHA;
    int* rep     = (int*)(ws + F_REP);
    int* drop    = (int*)(ws + F_DROP);
    int* pos     = (int*)(ws + F_POS);

    prep_all<<<NBLK_A + NBLK_B + NCAT, 256, 0, stream>>>(
        x, wm, wi, gm, gi, bm, bi, b1, Ah, Al, Bh, Bl, bias, logit);
    gemm_mfma<<<(NTOK / 128) * (NCAT / 128), 256, 0, stream>>>(Ah, Al, Bh, Bl, bias, w2, mbuf, logit);
    simgreedy<<<(B_ * NW_) / 4, 256, 0, stream>>>(mbuf, iidx, jidx, sv);
    select_fused<<<B_, 1024, 0, stream>>>(sv, iidx, jidx, logit, b2, alpha, rep, drop, pos);
    dim3 pgrid(T_, B_);
    pack_kernel<<<pgrid, 256, 0, stream>>>(x, drop, pos, rep, alpha, jidx, out);
  } else {
    // -------- fallback: fp32 vector-ALU path --------
    float* Wcat = ws + OFF_WCAT;
    float* bias = ws + OFF_BIAS;
    float* mu   = ws + OFF_MU;
    float* rs   = ws + OFF_RS;
    float* mbuf = ws + OFF_MBUF;
    float* logit = ws + OFF_LOGIT;
    int* iidx   = (int*)(ws + OFF_IIDX);
    int* jidx   = (int*)(ws + OFF_JIDX);
    float* sv   = ws + OFF_SV;
    float* alpha = ws + OFF_ALPHA;
    int* rep    = (int*)(ws + OFF_REP);
    int* drop   = (int*)(ws + OFF_DROP);
    int* pos    = (int*)(ws + OFF_POS);

    hipMemsetAsync(logit, 0, NTOK * sizeof(float), stream);
    build_wcat<<<(DIM_ * NCAT + 255) / 256, 256, 0, stream>>>(wm, wi, gm, gi, Wcat);
    build_bias<<<NCAT, 256, 0, stream>>>(wm, wi, bm, bi, b1, bias);
    ln_stats<<<NTOK / 4, 256, 0, stream>>>(x, mu, rs);
    dim3 ggrid(NTOK / 64, NCAT / 64);
    gemm640<<<ggrid, 256, 0, stream>>>(x, mu, rs, Wcat, bias, w2, mbuf, logit);
    simgreedy<<<(B_ * NW_) / 4, 256, 0, stream>>>(mbuf, iidx, jidx, sv);
    select_fused<<<B_, 1024, 0, stream>>>(sv, iidx, jidx, logit, b2, alpha, rep, drop, pos);
    dim3 pgrid(T_, B_);
    pack_kernel<<<pgrid, 256, 0, stream>>>(x, drop, pos, rep, alpha, jidx, out);
  }
}